// Round 1
// baseline (550.105 us; speedup 1.0000x reference)
//
#include <hip/hip_runtime.h>
#include <cstdint>
#include <cstddef>

// ---------------------------------------------------------------------------
// GCN 2-layer, N=100k nodes, E=1.6M edges, F=64 everywhere, fp32.
//
// Math: with dis[n] = rsqrt(deg_in[n]+1) (self-loop included),
//   g = (X @ W) * dis[row]
//   out[n] = dis[n] * ( sum_{e: dst=n} g[src(e)] + g[n] ) + b    (+ relu L1)
// Self-loop handled analytically (the +g[n] term), so CSR covers only the
// 1.6M real edges. CSR rebuilt every launch (no cross-call state).
// ---------------------------------------------------------------------------

__global__ void k_count(const int* __restrict__ dst, int* __restrict__ cnt, int E) {
    int e = blockIdx.x * blockDim.x + threadIdx.x;
    if (e < E) atomicAdd(&cnt[dst[e]], 1);
}

// Pass A: per-1024-chunk exclusive scan + chunk totals
__global__ void k_scan_a(const int* __restrict__ cnt, int* __restrict__ ex,
                         int* __restrict__ bsums, int n) {
    __shared__ int tmp[1024];
    int t = threadIdx.x;
    int i = blockIdx.x * 1024 + t;
    int v = (i < n) ? cnt[i] : 0;
    tmp[t] = v;
    __syncthreads();
    for (int off = 1; off < 1024; off <<= 1) {
        int a = (t >= off) ? tmp[t - off] : 0;
        __syncthreads();
        tmp[t] += a;
        __syncthreads();
    }
    if (i < n) ex[i] = tmp[t] - v;          // exclusive within chunk
    if (t == 1023) bsums[blockIdx.x] = tmp[1023];  // chunk total
}

// Pass B: exclusive scan of chunk totals (nb <= 256)
__global__ void k_scan_b(int* __restrict__ bsums, int nb) {
    __shared__ int tmp[256];
    int t = threadIdx.x;
    int v = (t < nb) ? bsums[t] : 0;
    tmp[t] = v;
    __syncthreads();
    for (int off = 1; off < 256; off <<= 1) {
        int a = (t >= off) ? tmp[t - off] : 0;
        __syncthreads();
        tmp[t] += a;
        __syncthreads();
    }
    if (t < nb) bsums[t] = tmp[t] - v;      // exclusive, in place
}

// Pass C: row_ptr = ex + chunk offset; init cursor; dis = rsqrt(deg+1)
__global__ void k_finish_csr(const int* __restrict__ ex, const int* __restrict__ bsums,
                             const int* __restrict__ cnt, int* __restrict__ rp,
                             int* __restrict__ cursor, float* __restrict__ dis, int n) {
    int i = blockIdx.x * blockDim.x + threadIdx.x;
    if (i >= n) return;
    int s = ex[i] + bsums[i >> 10];
    rp[i] = s;
    cursor[i] = s;
    dis[i] = rsqrtf((float)(cnt[i] + 1));
}

__global__ void k_fill(const int* __restrict__ src, const int* __restrict__ dst,
                       int* __restrict__ cursor, int* __restrict__ col, int E) {
    int e = blockIdx.x * blockDim.x + threadIdx.x;
    if (e < E) {
        int pos = atomicAdd(&cursor[dst[e]], 1);
        col[pos] = src[e];
    }
}

// out[row] = (X[row] @ W) * dis[row].  Thread-per-row, 64 fp32 accumulators.
// W[k*64+j] is wave-uniform -> scalar loads (s_load) expected.
__global__ void __launch_bounds__(256) k_gemm64(const float* __restrict__ X,
                                                const float* __restrict__ W,
                                                const float* __restrict__ dis,
                                                float* __restrict__ out, int n) {
    int row = blockIdx.x * blockDim.x + threadIdx.x;
    if (row >= n) return;
    const float4* xr = (const float4*)(X + (size_t)row * 64);
    float acc[64];
#pragma unroll
    for (int j = 0; j < 64; ++j) acc[j] = 0.f;
    for (int k4 = 0; k4 < 16; ++k4) {
        float4 xv = xr[k4];
        const float* w0 = W + k4 * 256;  // 4 consecutive k-rows of W
#pragma unroll
        for (int j = 0; j < 64; ++j) acc[j] = fmaf(xv.x, w0[j], acc[j]);
#pragma unroll
        for (int j = 0; j < 64; ++j) acc[j] = fmaf(xv.y, w0[64 + j], acc[j]);
#pragma unroll
        for (int j = 0; j < 64; ++j) acc[j] = fmaf(xv.z, w0[128 + j], acc[j]);
#pragma unroll
        for (int j = 0; j < 64; ++j) acc[j] = fmaf(xv.w, w0[192 + j], acc[j]);
    }
    float s = dis[row];
    float4* o = (float4*)(out + (size_t)row * 64);
#pragma unroll
    for (int j4 = 0; j4 < 16; ++j4) {
        float4 r;
        r.x = acc[j4 * 4 + 0] * s;
        r.y = acc[j4 * 4 + 1] * s;
        r.z = acc[j4 * 4 + 2] * s;
        r.w = acc[j4 * 4 + 3] * s;
        o[j4] = r;
    }
}

// One wave per node, lane = feature. Register accumulation, no atomics.
template <int RELU>
__global__ void __launch_bounds__(256) k_agg(const float* __restrict__ g,
                                             const int* __restrict__ col,
                                             const int* __restrict__ rp,
                                             const int* __restrict__ cnt,
                                             const float* __restrict__ dis,
                                             const float* __restrict__ bias,
                                             float* __restrict__ out, int n) {
    int node = blockIdx.x * 4 + (threadIdx.x >> 6);
    int lane = threadIdx.x & 63;
    if (node >= n) return;                   // wave-uniform branch
    int start = rp[node];
    int deg = cnt[node];
    float acc = g[(size_t)node * 64 + lane]; // self-loop term
    for (int base = 0; base < deg; base += 64) {
        int rem = deg - base;
        int m = rem < 64 ? rem : 64;
        int sv = (lane < m) ? col[start + base + lane] : 0;
        for (int i = 0; i < m; ++i) {
            int s = __shfl(sv, i);
            acc += g[(size_t)s * 64 + lane]; // coalesced 256B row gather
        }
    }
    float r = dis[node] * acc + bias[lane];
    if (RELU) r = fmaxf(r, 0.f);
    out[(size_t)node * 64 + lane] = r;
}

extern "C" void kernel_launch(void* const* d_in, const int* in_sizes, int n_in,
                              void* d_out, int out_size, void* d_ws, size_t ws_size,
                              hipStream_t stream) {
    const float* x  = (const float*)d_in[0];
    const int*   ei = (const int*)d_in[1];
    const float* W1 = (const float*)d_in[2];
    const float* b1 = (const float*)d_in[3];
    const float* W2 = (const float*)d_in[4];
    const float* b2 = (const float*)d_in[5];
    float* out = (float*)d_out;

    const int N = in_sizes[0] / 64;
    const int E = in_sizes[1] / 2;
    const int* src = ei;
    const int* dst = ei + E;

    char* ws = (char*)d_ws;
    size_t off = 0;
    auto alloc = [&](size_t bytes) -> void* {
        void* p = ws + off;
        off = (off + bytes + 255) & ~(size_t)255;
        return p;
    };
    int*   cnt    = (int*)  alloc((size_t)N * 4);
    int*   ex     = (int*)  alloc((size_t)N * 4);
    int*   rp     = (int*)  alloc((size_t)N * 4);
    int*   cursor = (int*)  alloc((size_t)N * 4);
    float* dis    = (float*)alloc((size_t)N * 4);
    int*   bsums  = (int*)  alloc(1024);
    int*   col    = (int*)  alloc((size_t)E * 4);
    float* g      = (float*)alloc((size_t)N * 64 * 4);
    float* h      = (float*)alloc((size_t)N * 64 * 4);
    (void)ws_size;

    const int tb = 256;
    hipMemsetAsync(cnt, 0, (size_t)N * 4, stream);
    k_count<<<(E + tb - 1) / tb, tb, 0, stream>>>(dst, cnt, E);
    int nb = (N + 1023) / 1024;
    k_scan_a<<<nb, 1024, 0, stream>>>(cnt, ex, bsums, N);
    k_scan_b<<<1, 256, 0, stream>>>(bsums, nb);
    k_finish_csr<<<(N + tb - 1) / tb, tb, 0, stream>>>(ex, bsums, cnt, rp, cursor, dis, N);
    k_fill<<<(E + tb - 1) / tb, tb, 0, stream>>>(src, dst, cursor, col, E);

    // Layer 1: g = (x@W1)*dis ; h = relu(dis*(agg+g)+b1)
    k_gemm64<<<(N + tb - 1) / tb, tb, 0, stream>>>(x, W1, dis, g, N);
    k_agg<1><<<(N + 3) / 4, 256, 0, stream>>>(g, col, rp, cnt, dis, b1, h, N);

    // Layer 2: g = (h@W2)*dis ; out = dis*(agg+g)+b2
    k_gemm64<<<(N + tb - 1) / tb, tb, 0, stream>>>(h, W2, dis, g, N);
    k_agg<0><<<(N + 3) / 4, 256, 0, stream>>>(g, col, rp, cnt, dis, b2, out, N);
}

// Round 2
// 320.604 us; speedup vs baseline: 1.7158x; 1.7158x over previous
//
#include <hip/hip_runtime.h>
#include <cstdint>
#include <cstddef>

// ---------------------------------------------------------------------------
// GCN 2-layer, N=100k nodes, E=1.6M edges, F=64, fp32 in/out.
//
//   dis[n] = rsqrt(in_deg[n]+1)            (self-loop folded in analytically)
//   g = bf16( (X @ W) * dis[row] )
//   out[n] = dis[n] * ( sum_{e: dst=n} g[src(e)] + g[n] ) + b   (+ relu L1)
//
// CSR build via bucketed counting sort (buckets of 512 dst nodes) so all
// scatter writes land in small L2-resident windows (fixes the 105 MB
// write-amplification k_fill showed in round 1).
// ---------------------------------------------------------------------------

#define BK_SHIFT 9                // 512 nodes per bucket
#define BK_NODES 512
#define EPB 8192                  // edges per scatter block

static __device__ __forceinline__ unsigned short f2b(float f) {
    unsigned x = __float_as_uint(f);
    unsigned r = (x + 0x7FFFu + ((x >> 16) & 1u)) >> 16;   // RNE
    return (unsigned short)r;
}
static __device__ __forceinline__ float b2f(unsigned short u) {
    return __uint_as_float(((unsigned)u) << 16);
}

// ---- Pass A: bucket histogram (LDS hist per block -> global atomic) -------
__global__ void __launch_bounds__(256) k_bhist(const int* __restrict__ dst,
                                               int* __restrict__ bcnt, int E, int NB) {
    __shared__ int hist[1024];
    for (int i = threadIdx.x; i < NB; i += 256) hist[i] = 0;
    __syncthreads();
    int stride = gridDim.x * 256;
    for (int e = blockIdx.x * 256 + threadIdx.x; e < E; e += stride)
        atomicAdd(&hist[dst[e] >> BK_SHIFT], 1);
    __syncthreads();
    for (int i = threadIdx.x; i < NB; i += 256) {
        int c = hist[i];
        if (c) atomicAdd(&bcnt[i], c);
    }
}

// ---- Pass B: exclusive scan of bucket sizes (single block) ----------------
__global__ void __launch_bounds__(1024) k_bscan(const int* __restrict__ bcnt,
                                                int* __restrict__ bbase,
                                                int* __restrict__ gcursor,
                                                int* __restrict__ rp,
                                                int NB, int N, int E) {
    __shared__ int tmp[1024];
    int t = threadIdx.x;
    int v = (t < NB) ? bcnt[t] : 0;
    tmp[t] = v;
    __syncthreads();
    for (int off = 1; off < 1024; off <<= 1) {
        int a = (t >= off) ? tmp[t - off] : 0;
        __syncthreads();
        tmp[t] += a;
        __syncthreads();
    }
    if (t < NB) {
        int ex = tmp[t] - v;
        bbase[t] = ex;
        gcursor[t] = ex;
    }
    if (t == 0) { bbase[NB] = E; rp[N] = E; }
}

// ---- Pass C: scatter edges into bucket-ordered store, packed uint32 -------
// pack = src (17 bits) | dst_local (9 bits) << 17   (N <= 131072)
__global__ void __launch_bounds__(256) k_bscatter(const int* __restrict__ src,
                                                  const int* __restrict__ dst,
                                                  int* __restrict__ gcursor,
                                                  unsigned* __restrict__ packed,
                                                  int E, int NB) {
    __shared__ int hist[1024];
    __shared__ int base[1024];
    for (int i = threadIdx.x; i < NB; i += 256) hist[i] = 0;
    __syncthreads();
    int e0 = blockIdx.x * EPB;
    int e1 = min(e0 + EPB, E);
    for (int e = e0 + threadIdx.x; e < e1; e += 256)
        atomicAdd(&hist[dst[e] >> BK_SHIFT], 1);
    __syncthreads();
    for (int i = threadIdx.x; i < NB; i += 256) {
        int c = hist[i];
        base[i] = c ? atomicAdd(&gcursor[i], c) : 0;
        hist[i] = 0;
    }
    __syncthreads();
    for (int e = e0 + threadIdx.x; e < e1; e += 256) {
        int d = dst[e];
        int s = src[e];
        int bkt = d >> BK_SHIFT;
        int pos = base[bkt] + atomicAdd(&hist[bkt], 1);
        packed[pos] = (unsigned)s | (((unsigned)d & (BK_NODES - 1)) << 17);
    }
}

// ---- Pass D: per-bucket CSR build (one block per bucket, local windows) ---
__global__ void __launch_bounds__(512) k_build(const unsigned* __restrict__ packed,
                                               const int* __restrict__ bbase,
                                               int* __restrict__ rp,
                                               float* __restrict__ dis,
                                               int* __restrict__ col, int N) {
    __shared__ int cnt_s[BK_NODES];
    __shared__ int tmp[BK_NODES];
    int b = blockIdx.x;
    int t = threadIdx.x;
    int node0 = b << BK_SHIFT;
    int nnode = min(BK_NODES, N - node0);
    int e0 = bbase[b], e1 = bbase[b + 1];
    cnt_s[t] = 0;
    __syncthreads();
    for (int e = e0 + t; e < e1; e += 512)
        atomicAdd(&cnt_s[packed[e] >> 17], 1);
    __syncthreads();
    int v = cnt_s[t];
    tmp[t] = v;
    __syncthreads();
    for (int off = 1; off < BK_NODES; off <<= 1) {
        int a = (t >= off) ? tmp[t - off] : 0;
        __syncthreads();
        tmp[t] += a;
        __syncthreads();
    }
    int excl = tmp[t] - v;
    if (t < nnode) {
        rp[node0 + t] = e0 + excl;
        dis[node0 + t] = rsqrtf((float)(v + 1));
    }
    __syncthreads();
    cnt_s[t] = excl;               // reuse as local cursor
    __syncthreads();
    for (int e = e0 + t; e < e1; e += 512) {
        unsigned p = packed[e];
        int dl = (int)(p >> 17);
        int pos = atomicAdd(&cnt_s[dl], 1);
        col[e0 + pos] = (int)(p & 0x1FFFFu);
    }
}

// ---- GEMM: g16[row] = bf16( (X[row] @ W) * dis[row] ) ---------------------
__global__ void __launch_bounds__(256) k_gemm64(const float* __restrict__ X,
                                                const float* __restrict__ W,
                                                const float* __restrict__ dis,
                                                unsigned short* __restrict__ g16, int n) {
    int row = blockIdx.x * blockDim.x + threadIdx.x;
    if (row >= n) return;
    const float4* xr = (const float4*)(X + (size_t)row * 64);
    float acc[64];
#pragma unroll
    for (int j = 0; j < 64; ++j) acc[j] = 0.f;
    for (int k4 = 0; k4 < 16; ++k4) {
        float4 xv = xr[k4];
        const float* w0 = W + k4 * 256;
#pragma unroll
        for (int j = 0; j < 64; ++j) acc[j] = fmaf(xv.x, w0[j], acc[j]);
#pragma unroll
        for (int j = 0; j < 64; ++j) acc[j] = fmaf(xv.y, w0[64 + j], acc[j]);
#pragma unroll
        for (int j = 0; j < 64; ++j) acc[j] = fmaf(xv.z, w0[128 + j], acc[j]);
#pragma unroll
        for (int j = 0; j < 64; ++j) acc[j] = fmaf(xv.w, w0[192 + j], acc[j]);
    }
    float s = dis[row];
    uint4* o = (uint4*)(g16 + (size_t)row * 64);
#pragma unroll
    for (int j8 = 0; j8 < 8; ++j8) {
        uint4 p;
        p.x = (unsigned)f2b(acc[j8 * 8 + 0] * s) | ((unsigned)f2b(acc[j8 * 8 + 1] * s) << 16);
        p.y = (unsigned)f2b(acc[j8 * 8 + 2] * s) | ((unsigned)f2b(acc[j8 * 8 + 3] * s) << 16);
        p.z = (unsigned)f2b(acc[j8 * 8 + 4] * s) | ((unsigned)f2b(acc[j8 * 8 + 5] * s) << 16);
        p.w = (unsigned)f2b(acc[j8 * 8 + 6] * s) | ((unsigned)f2b(acc[j8 * 8 + 7] * s) << 16);
        o[j8] = p;
    }
}

// ---- Aggregate: one wave per node, lane = feature, 4 accumulators ---------
template <int RELU>
__global__ void __launch_bounds__(256) k_agg(const unsigned short* __restrict__ g16,
                                             const int* __restrict__ col,
                                             const int* __restrict__ rp,
                                             const float* __restrict__ dis,
                                             const float* __restrict__ bias,
                                             float* __restrict__ out, int n) {
    int node = blockIdx.x * 4 + (threadIdx.x >> 6);
    int lane = threadIdx.x & 63;
    if (node >= n) return;                   // wave-uniform
    int start = rp[node];
    int deg = rp[node + 1] - start;
    float a0 = b2f(g16[(size_t)node * 64 + lane]);   // self-loop term
    float a1 = 0.f, a2 = 0.f, a3 = 0.f;
    for (int base = 0; base < deg; base += 64) {
        int rem = deg - base;
        int m = rem < 64 ? rem : 64;
        int sv = (lane < m) ? col[start + base + lane] : 0;
        int i = 0;
        for (; i + 4 <= m; i += 4) {
            int s0 = __shfl(sv, i);
            int s1 = __shfl(sv, i + 1);
            int s2 = __shfl(sv, i + 2);
            int s3 = __shfl(sv, i + 3);
            a0 += b2f(g16[(size_t)s0 * 64 + lane]);
            a1 += b2f(g16[(size_t)s1 * 64 + lane]);
            a2 += b2f(g16[(size_t)s2 * 64 + lane]);
            a3 += b2f(g16[(size_t)s3 * 64 + lane]);
        }
        for (; i < m; ++i)
            a0 += b2f(g16[(size_t)__shfl(sv, i) * 64 + lane]);
    }
    float r = dis[node] * (a0 + a1 + a2 + a3) + bias[lane];
    if (RELU) r = fmaxf(r, 0.f);
    out[(size_t)node * 64 + lane] = r;
}

extern "C" void kernel_launch(void* const* d_in, const int* in_sizes, int n_in,
                              void* d_out, int out_size, void* d_ws, size_t ws_size,
                              hipStream_t stream) {
    const float* x  = (const float*)d_in[0];
    const int*   ei = (const int*)d_in[1];
    const float* W1 = (const float*)d_in[2];
    const float* b1 = (const float*)d_in[3];
    const float* W2 = (const float*)d_in[4];
    const float* b2 = (const float*)d_in[5];
    float* out = (float*)d_out;

    const int N = in_sizes[0] / 64;
    const int E = in_sizes[1] / 2;
    const int NB = (N + BK_NODES - 1) >> BK_SHIFT;
    const int* src = ei;
    const int* dst = ei + E;

    char* ws = (char*)d_ws;
    size_t off = 0;
    auto alloc = [&](size_t bytes) -> void* {
        void* p = ws + off;
        off = (off + bytes + 255) & ~(size_t)255;
        return p;
    };
    int*            bcnt    = (int*)alloc((size_t)(NB + 1) * 4);
    int*            bbase   = (int*)alloc((size_t)(NB + 1) * 4);
    int*            gcursor = (int*)alloc((size_t)NB * 4);
    int*            rp      = (int*)alloc((size_t)(N + 1) * 4);
    float*          dis     = (float*)alloc((size_t)N * 4);
    unsigned*       packed  = (unsigned*)alloc((size_t)E * 4);
    int*            col     = (int*)alloc((size_t)E * 4);
    unsigned short* g16     = (unsigned short*)alloc((size_t)N * 64 * 2);
    float*          h       = (float*)alloc((size_t)N * 64 * 4);
    (void)ws_size;

    hipMemsetAsync(bcnt, 0, (size_t)NB * 4, stream);
    k_bhist<<<512, 256, 0, stream>>>(dst, bcnt, E, NB);
    k_bscan<<<1, 1024, 0, stream>>>(bcnt, bbase, gcursor, rp, NB, N, E);
    k_bscatter<<<(E + EPB - 1) / EPB, 256, 0, stream>>>(src, dst, gcursor, packed, E, NB);
    k_build<<<NB, 512, 0, stream>>>(packed, bbase, rp, dis, col, N);

    const int tb = 256;
    // Layer 1
    k_gemm64<<<(N + tb - 1) / tb, tb, 0, stream>>>(x, W1, dis, g16, N);
    k_agg<1><<<(N + 3) / 4, 256, 0, stream>>>(g16, col, rp, dis, b1, h, N);
    // Layer 2
    k_gemm64<<<(N + tb - 1) / tb, tb, 0, stream>>>(h, W2, dis, g16, N);
    k_agg<0><<<(N + 3) / 4, 256, 0, stream>>>(g16, col, rp, dis, b2, out, N);
}